// Round 4
// baseline (1415.984 us; speedup 1.0000x reference)
//
#include <hip/hip_runtime.h>
#include <math.h>

#define NB 46
#define NS 50
#define ND 768
#define GAMA 0.96875f
#define NM 2300   // NB*NS rows

typedef float v2f __attribute__((ext_vector_type(2)));

// ---------------- Kernel 1: QKV projections (+bias, +pe for Q,K) ----------
__global__ __launch_bounds__(256) void qkv_gemm(
    const float* __restrict__ text_emb, const float* __restrict__ emb,
    const float* __restrict__ Wq, const float* __restrict__ bq,
    const float* __restrict__ Wk, const float* __restrict__ bk,
    const float* __restrict__ Wv, const float* __restrict__ bv,
    float* __restrict__ Q, float* __restrict__ K, float* __restrict__ V)
{
    const int z = blockIdx.z;
    const float* X    = (z == 0) ? text_emb : emb;
    const float* W    = (z == 0) ? Wq : (z == 1) ? Wk : Wv;
    const float* bias = (z == 0) ? bq : (z == 1) ? bk : bv;
    float* out        = (z == 0) ? Q  : (z == 1) ? K  : V;

    __shared__ float Xs[16][68];
    __shared__ float Ws[16][68];

    const int tid = threadIdx.x;
    const int tx = tid & 15, ty = tid >> 4;
    const int m0 = blockIdx.x * 64, n0 = blockIdx.y * 64;

    const int lrow = tid >> 2;        // 0..63
    const int lk   = (tid & 3) * 4;   // 0,4,8,12

    float acc[4][4];
    #pragma unroll
    for (int i = 0; i < 4; i++)
        #pragma unroll
        for (int j = 0; j < 4; j++) acc[i][j] = 0.f;

    for (int k0 = 0; k0 < ND; k0 += 16) {
        float4 xv = make_float4(0.f, 0.f, 0.f, 0.f);
        const int xm = m0 + lrow;
        if (xm < NM) xv = *reinterpret_cast<const float4*>(&X[xm * ND + k0 + lk]);
        const float4 wv = *reinterpret_cast<const float4*>(&W[(n0 + lrow) * ND + k0 + lk]);
        Xs[lk + 0][lrow] = xv.x; Xs[lk + 1][lrow] = xv.y;
        Xs[lk + 2][lrow] = xv.z; Xs[lk + 3][lrow] = xv.w;
        Ws[lk + 0][lrow] = wv.x; Ws[lk + 1][lrow] = wv.y;
        Ws[lk + 2][lrow] = wv.z; Ws[lk + 3][lrow] = wv.w;
        __syncthreads();
        #pragma unroll
        for (int k = 0; k < 16; k++) {
            const float4 a  = *reinterpret_cast<const float4*>(&Xs[k][4 * ty]);
            const float4 b4 = *reinterpret_cast<const float4*>(&Ws[k][4 * tx]);
            const float av[4]  = {a.x,  a.y,  a.z,  a.w};
            const float bv4[4] = {b4.x, b4.y, b4.z, b4.w};
            #pragma unroll
            for (int i = 0; i < 4; i++)
                #pragma unroll
                for (int j = 0; j < 4; j++) acc[i][j] += av[i] * bv4[j];
        }
        __syncthreads();
    }

    const float C2 = -0.0239861701969175f; // -2*ln(10000)/768
    #pragma unroll
    for (int i = 0; i < 4; i++) {
        const int m = m0 + 4 * ty + i;
        if (m >= NM) continue;
        const int bpos = m / NS;  // pe indexed by BATCH position (faithful to source)
        #pragma unroll
        for (int j = 0; j < 4; j++) {
            const int n = n0 + 4 * tx + j;
            float v = acc[i][j] + bias[n];
            if (z < 2) {
                const int h = n >> 1;
                const float ang = (float)bpos * expf((float)h * C2);
                v += (n & 1) ? cosf(ang) : sinf(ang);
            }
            out[m * ND + n] = v;
        }
    }
}

// ---------------- Kernel 2: scores+softmax+ctx, and Ag = gamma*Q_trans -----
__global__ __launch_bounds__(64) void attn(
    const float* __restrict__ Q, const float* __restrict__ K,
    const float* __restrict__ V,
    const float* __restrict__ lin_w, const float* __restrict__ lin_b,
    float* __restrict__ Ag, float* __restrict__ ctx_out)
{
    const int bq = blockIdx.x;
    const int b = bq / NS, q = bq % NS;
    const int lane = threadIdx.x;

    const float* Qr = Q + (b * NS + q) * ND;
    float qv[12];
    #pragma unroll
    for (int m = 0; m < 12; m++) qv[m] = Qr[m * 64 + lane];

    // scores: lane k ends up holding score[k]*8
    float mysc = 0.f;
    for (int k = 0; k < NS; k++) {
        const float* Kr = K + (b * NS + k) * ND;
        float s = 0.f;
        #pragma unroll
        for (int m = 0; m < 12; m++) s += qv[m] * Kr[m * 64 + lane];
        #pragma unroll
        for (int off = 32; off; off >>= 1) s += __shfl_xor(s, off);
        if (lane == k) mysc = s * 8.f;
    }
    // Q_trans row q: lane j holds Qt[j]; write Ag = gamma*(Qt + lin_b)
    float myqt = 0.f;
    for (int j = 0; j < NS; j++) {
        const float* Lr = lin_w + j * ND;
        float s = 0.f;
        #pragma unroll
        for (int m = 0; m < 12; m++) s += qv[m] * Lr[m * 64 + lane];
        #pragma unroll
        for (int off = 32; off; off >>= 1) s += __shfl_xor(s, off);
        if (lane == j) myqt = s;
    }
    if (lane < NS)
        Ag[b * (NS * NS) + q * NS + lane] = GAMA * (myqt + lin_b[lane]);

    // softmax over lanes 0..49
    const float sc = (lane < NS) ? mysc : -INFINITY;
    float mx = sc;
    #pragma unroll
    for (int off = 32; off; off >>= 1) mx = fmaxf(mx, __shfl_xor(mx, off));
    const float e = (lane < NS) ? expf(sc - mx) : 0.f;
    float sum = e;
    #pragma unroll
    for (int off = 32; off; off >>= 1) sum += __shfl_xor(sum, off);
    const float p = e / sum;

    // ctx row = sum_k p_k * V[b,k,:]
    float acc[12];
    #pragma unroll
    for (int m = 0; m < 12; m++) acc[m] = 0.f;
    for (int k = 0; k < NS; k++) {
        const float pk = __shfl(p, k);
        const float* Vr = V + (b * NS + k) * ND;
        #pragma unroll
        for (int m = 0; m < 12; m++) acc[m] += pk * Vr[m * 64 + lane];
    }
    float* Cr = ctx_out + (b * NS + q) * ND;
    #pragma unroll
    for (int m = 0; m < 12; m++) Cr[m * 64 + lane] = acc[m];
}

// ---------------- Kernel 3: gamma-decay recurrence --------------------------
// rec[i,b,:,:] = Ag_b @ rec[i-1,b,:,:] + ctx[i].
// Barrier-free, one wave per (b, 64-col chunk); state in registers as float2
// pairs (v_pk_fma_f32 path). R3 lesson: 256 VGPR is the architectural cap and
// preloading cv[50] starved the LDS pipeline -> rolling prefetch (dist 8)
// keeps live state ~150 regs so ds_reads can stay in flight.
#define PF 8
__global__ __launch_bounds__(64, 1) void recur(
    const float* __restrict__ Ag, const float* __restrict__ ctx,
    float* __restrict__ rec)
{
    const int blk   = blockIdx.x;
    const int b     = blk / 12;
    const int chunk = blk - b * 12;
    const int lane  = threadIdx.x;
    const int d     = chunk * 64 + lane;

    __shared__ float Als[NS * 52];   // 10.4 KB, rows padded 50->52 (16B-aligned)

    const float* __restrict__ Ab = Ag + b * (NS * NS);
    for (int idx = lane; idx < NS * NS; idx += 64) {
        const int r = idx / NS, j = idx - r * NS;
        Als[r * 52 + j] = Ab[idx];
    }
    __syncthreads();   // once, outside the step loop

    v2f s2[25];        // state pairs: s2[p] = {s[2p], s[2p+1]}
    float cv[NS];

    // ---- step 0: s_0 = ctx[0] ----
    #pragma unroll
    for (int r = 0; r < NS; r++) cv[r] = ctx[r * ND + d];
    #pragma unroll
    for (int r = 0; r < NS; r++)
        __builtin_nontemporal_store(cv[r], &rec[(b * NS + r) * ND + d]);
    #pragma unroll
    for (int p = 0; p < 25; p++) { s2[p].x = cv[2 * p]; s2[p].y = cv[2 * p + 1]; }

    for (int i = 1; i < NB; ++i) {
        const float* __restrict__ ctxi = ctx + i * NS * ND + d;
        float* __restrict__ reci = rec + (i * NB + b) * NS * ND + d;
        float sn[NS];

        // prime the rolling ctx prefetch
        #pragma unroll
        for (int r = 0; r < PF; r++) cv[r] = ctxi[r * ND];

        #pragma unroll
        for (int r = 0; r < NS; r++) {
            if (r + PF < NS) cv[r + PF] = ctxi[(r + PF) * ND];
            const float* __restrict__ Ar = &Als[r * 52];
            v2f acc01; acc01.x = 0.f; acc01.y = 0.f;   // chains j%4==0 / j%4==1
            v2f acc23; acc23.x = 0.f; acc23.y = 0.f;   // chains j%4==2 / j%4==3
            #pragma unroll
            for (int jj = 0; jj < 48; jj += 4) {
                const float4 a4 = *reinterpret_cast<const float4*>(Ar + jj);
                v2f a01; a01.x = a4.x; a01.y = a4.y;
                v2f a23; a23.x = a4.z; a23.y = a4.w;
                acc01 += a01 * s2[jj / 2];
                acc23 += a23 * s2[jj / 2 + 1];
            }
            {   // j = 48, 49 (pad lanes unused)
                const float4 a4 = *reinterpret_cast<const float4*>(Ar + 48);
                v2f a01; a01.x = a4.x; a01.y = a4.y;
                acc01 += a01 * s2[24];
            }
            // ((s0+s2)+(s1+s3)) + cv  — identical order to R2/R3
            const float v = ((acc01.x + acc23.x) + (acc01.y + acc23.y)) + cv[r];
            sn[r] = v;
            __builtin_nontemporal_store(v, &reci[r * ND]);
        }

        #pragma unroll
        for (int p = 0; p < 25; p++) { s2[p].x = sn[2 * p]; s2[p].y = sn[2 * p + 1]; }
    }
}

extern "C" void kernel_launch(void* const* d_in, const int* in_sizes, int n_in,
                              void* d_out, int out_size, void* d_ws, size_t ws_size,
                              hipStream_t stream) {
    const float* text_emb = (const float*)d_in[0];
    const float* emb      = (const float*)d_in[1];
    const float* Wq = (const float*)d_in[2]; const float* bq = (const float*)d_in[3];
    const float* Wk = (const float*)d_in[4]; const float* bk = (const float*)d_in[5];
    const float* Wv = (const float*)d_in[6]; const float* bv = (const float*)d_in[7];
    const float* lw = (const float*)d_in[8]; const float* lb = (const float*)d_in[9];

    float* out = (float*)d_out;
    float* ctx = out;                          // [46,50,768]
    float* rec = out + NB * NS * ND;           // [46,46,50,768]

    float* ws = (float*)d_ws;                  // needs 21.7 MB
    float* Q  = ws;
    float* K  = Q + NB * NS * ND;
    float* V  = K + NB * NS * ND;
    float* Ag = V + NB * NS * ND;              // gamma * Q_trans, [46,50,50]

    qkv_gemm<<<dim3(36, 12, 3), 256, 0, stream>>>(text_emb, emb, Wq, bq, Wk, bk, Wv, bv, Q, K, V);
    attn<<<dim3(NM), 64, 0, stream>>>(Q, K, V, lw, lb, Ag, ctx);
    recur<<<dim3(552), 64, 0, stream>>>(Ag, ctx, rec);
}

// Round 5
// 605.401 us; speedup vs baseline: 2.3389x; 2.3389x over previous
//
#include <hip/hip_runtime.h>
#include <math.h>

#define NB 46
#define NS 50
#define ND 768
#define GAMA 0.96875f
#define NM 2300   // NB*NS rows

typedef float v2f __attribute__((ext_vector_type(2)));

// ---------------- Kernel 1: QKV projections (+bias, +pe for Q,K) ----------
__global__ __launch_bounds__(256) void qkv_gemm(
    const float* __restrict__ text_emb, const float* __restrict__ emb,
    const float* __restrict__ Wq, const float* __restrict__ bq,
    const float* __restrict__ Wk, const float* __restrict__ bk,
    const float* __restrict__ Wv, const float* __restrict__ bv,
    float* __restrict__ Q, float* __restrict__ K, float* __restrict__ V)
{
    const int z = blockIdx.z;
    const float* X    = (z == 0) ? text_emb : emb;
    const float* W    = (z == 0) ? Wq : (z == 1) ? Wk : Wv;
    const float* bias = (z == 0) ? bq : (z == 1) ? bk : bv;
    float* out        = (z == 0) ? Q  : (z == 1) ? K  : V;

    __shared__ float Xs[16][68];
    __shared__ float Ws[16][68];

    const int tid = threadIdx.x;
    const int tx = tid & 15, ty = tid >> 4;
    const int m0 = blockIdx.x * 64, n0 = blockIdx.y * 64;

    const int lrow = tid >> 2;        // 0..63
    const int lk   = (tid & 3) * 4;   // 0,4,8,12

    float acc[4][4];
    #pragma unroll
    for (int i = 0; i < 4; i++)
        #pragma unroll
        for (int j = 0; j < 4; j++) acc[i][j] = 0.f;

    for (int k0 = 0; k0 < ND; k0 += 16) {
        float4 xv = make_float4(0.f, 0.f, 0.f, 0.f);
        const int xm = m0 + lrow;
        if (xm < NM) xv = *reinterpret_cast<const float4*>(&X[xm * ND + k0 + lk]);
        const float4 wv = *reinterpret_cast<const float4*>(&W[(n0 + lrow) * ND + k0 + lk]);
        Xs[lk + 0][lrow] = xv.x; Xs[lk + 1][lrow] = xv.y;
        Xs[lk + 2][lrow] = xv.z; Xs[lk + 3][lrow] = xv.w;
        Ws[lk + 0][lrow] = wv.x; Ws[lk + 1][lrow] = wv.y;
        Ws[lk + 2][lrow] = wv.z; Ws[lk + 3][lrow] = wv.w;
        __syncthreads();
        #pragma unroll
        for (int k = 0; k < 16; k++) {
            const float4 a  = *reinterpret_cast<const float4*>(&Xs[k][4 * ty]);
            const float4 b4 = *reinterpret_cast<const float4*>(&Ws[k][4 * tx]);
            const float av[4]  = {a.x,  a.y,  a.z,  a.w};
            const float bv4[4] = {b4.x, b4.y, b4.z, b4.w};
            #pragma unroll
            for (int i = 0; i < 4; i++)
                #pragma unroll
                for (int j = 0; j < 4; j++) acc[i][j] += av[i] * bv4[j];
        }
        __syncthreads();
    }

    const float C2 = -0.0239861701969175f; // -2*ln(10000)/768
    #pragma unroll
    for (int i = 0; i < 4; i++) {
        const int m = m0 + 4 * ty + i;
        if (m >= NM) continue;
        const int bpos = m / NS;  // pe indexed by BATCH position (faithful to source)
        #pragma unroll
        for (int j = 0; j < 4; j++) {
            const int n = n0 + 4 * tx + j;
            float v = acc[i][j] + bias[n];
            if (z < 2) {
                const int h = n >> 1;
                const float ang = (float)bpos * expf((float)h * C2);
                v += (n & 1) ? cosf(ang) : sinf(ang);
            }
            out[m * ND + n] = v;
        }
    }
}

// ---------------- Kernel 2: scores+softmax+ctx, and Ag = gamma*Q_trans -----
__global__ __launch_bounds__(64) void attn(
    const float* __restrict__ Q, const float* __restrict__ K,
    const float* __restrict__ V,
    const float* __restrict__ lin_w, const float* __restrict__ lin_b,
    float* __restrict__ Ag, float* __restrict__ ctx_out)
{
    const int bq = blockIdx.x;
    const int b = bq / NS, q = bq % NS;
    const int lane = threadIdx.x;

    const float* Qr = Q + (b * NS + q) * ND;
    float qv[12];
    #pragma unroll
    for (int m = 0; m < 12; m++) qv[m] = Qr[m * 64 + lane];

    // scores: lane k ends up holding score[k]*8
    float mysc = 0.f;
    for (int k = 0; k < NS; k++) {
        const float* Kr = K + (b * NS + k) * ND;
        float s = 0.f;
        #pragma unroll
        for (int m = 0; m < 12; m++) s += qv[m] * Kr[m * 64 + lane];
        #pragma unroll
        for (int off = 32; off; off >>= 1) s += __shfl_xor(s, off);
        if (lane == k) mysc = s * 8.f;
    }
    // Q_trans row q: lane j holds Qt[j]; write Ag = gamma*(Qt + lin_b)
    float myqt = 0.f;
    for (int j = 0; j < NS; j++) {
        const float* Lr = lin_w + j * ND;
        float s = 0.f;
        #pragma unroll
        for (int m = 0; m < 12; m++) s += qv[m] * Lr[m * 64 + lane];
        #pragma unroll
        for (int off = 32; off; off >>= 1) s += __shfl_xor(s, off);
        if (lane == j) myqt = s;
    }
    if (lane < NS)
        Ag[b * (NS * NS) + q * NS + lane] = GAMA * (myqt + lin_b[lane]);

    // softmax over lanes 0..49
    const float sc = (lane < NS) ? mysc : -INFINITY;
    float mx = sc;
    #pragma unroll
    for (int off = 32; off; off >>= 1) mx = fmaxf(mx, __shfl_xor(mx, off));
    const float e = (lane < NS) ? expf(sc - mx) : 0.f;
    float sum = e;
    #pragma unroll
    for (int off = 32; off; off >>= 1) sum += __shfl_xor(sum, off);
    const float p = e / sum;

    // ctx row = sum_k p_k * V[b,k,:]
    float acc[12];
    #pragma unroll
    for (int m = 0; m < 12; m++) acc[m] = 0.f;
    for (int k = 0; k < NS; k++) {
        const float pk = __shfl(p, k);
        const float* Vr = V + (b * NS + k) * ND;
        #pragma unroll
        for (int m = 0; m < 12; m++) acc[m] += pk * Vr[m * 64 + lane];
    }
    float* Cr = ctx_out + (b * NS + q) * ND;
    #pragma unroll
    for (int m = 0; m < 12; m++) Cr[m * 64 + lane] = acc[m];
}

// ---------------- Kernel 3: gamma-decay recurrence --------------------------
// rec[i,b,:,:] = Ag_b @ rec[i-1,b,:,:] + ctx[i].
// Block = (b, 64-col chunk), 2 waves; wave w computes rows w*25..w*25+24.
// State round-trips through double-buffered LDS (one barrier/step). A is in
// LDS, read as uniform broadcast ds_read_b128 (NO s_load: SMEM's OOO returns
// force lgkmcnt(0) drains — R2's stall). Per-wave live regs ~90 (R3/R4 lesson:
// old+new state + ctx in regs busts the 256 cap and spills).
#define RPW 25
__global__ __launch_bounds__(128) void recur(
    const float* __restrict__ Ag, const float* __restrict__ ctx,
    float* __restrict__ rec)
{
    const int blk   = blockIdx.x;
    const int b     = blk / 12;
    const int chunk = blk - b * 12;
    const int tid   = threadIdx.x;
    const int lane  = tid & 63;
    const int wid   = tid >> 6;            // 0,1
    const int d     = chunk * 64 + lane;
    const int r0    = wid * RPW;           // 0,25

    __shared__ float Als[NS * 52];         // A rows padded 50->52 (16B-aligned)
    __shared__ float st[2][NS * 64];       // double-buffered state

    const float* __restrict__ Ab = Ag + b * (NS * NS);
    for (int idx = tid; idx < NS * NS; idx += 128) {
        const int r = idx / NS, j = idx - r * NS;
        Als[r * 52 + j] = Ab[idx];
    }

    // ---- step 0: s_0 = ctx[0] (each wave its 25 rows) ----
    #pragma unroll
    for (int k = 0; k < RPW; k++) {
        const int r = r0 + k;
        const float v = ctx[r * ND + d];
        st[0][r * 64 + lane] = v;
        __builtin_nontemporal_store(v, &rec[(b * NS + r) * ND + d]);
    }
    __syncthreads();   // also covers A staging

    int p = 0;
    for (int i = 1; i < NB; ++i) {
        // full old state -> registers as pairs (ds_read2_b32-mergeable)
        v2f s2[25];
        #pragma unroll
        for (int j = 0; j < 25; j++) {
            s2[j].x = st[p][(2 * j)     * 64 + lane];
            s2[j].y = st[p][(2 * j + 1) * 64 + lane];
        }

        const float* __restrict__ ctxi = ctx + i * NS * ND + d;
        float* __restrict__ reci = rec + (size_t)(i * NB + b) * NS * ND + d;

        // 8-slot rolling ctx buffer (all indices compile-time after unroll)
        float c8[8];
        #pragma unroll
        for (int k = 0; k < 8; k++) c8[k] = ctxi[(r0 + k) * ND];

        #pragma unroll
        for (int k = 0; k < RPW; k++) {
            const int r = r0 + k;
            const float* __restrict__ Ar = &Als[r * 52];
            v2f acc01; acc01.x = 0.f; acc01.y = 0.f;   // chains j%4==0 / 1
            v2f acc23; acc23.x = 0.f; acc23.y = 0.f;   // chains j%4==2 / 3
            #pragma unroll
            for (int jj = 0; jj < 48; jj += 4) {
                const float4 a4 = *reinterpret_cast<const float4*>(Ar + jj);
                v2f a01; a01.x = a4.x; a01.y = a4.y;
                v2f a23; a23.x = a4.z; a23.y = a4.w;
                acc01 += a01 * s2[jj / 2];
                acc23 += a23 * s2[jj / 2 + 1];
            }
            {   // j = 48,49 (pad lanes unused)
                const float4 a4 = *reinterpret_cast<const float4*>(Ar + 48);
                v2f a01; a01.x = a4.x; a01.y = a4.y;
                acc01 += a01 * s2[24];
            }
            // ((s0+s2)+(s1+s3)) + cv — identical order to R2/R3/R4
            const float v = ((acc01.x + acc23.x) + (acc01.y + acc23.y)) + c8[k & 7];
            if (k + 8 < RPW) c8[k & 7] = ctxi[(r0 + k + 8) * ND];
            st[p ^ 1][r * 64 + lane] = v;
            __builtin_nontemporal_store(v, &reci[r * ND]);
        }
        __syncthreads();
        p ^= 1;
    }
}

extern "C" void kernel_launch(void* const* d_in, const int* in_sizes, int n_in,
                              void* d_out, int out_size, void* d_ws, size_t ws_size,
                              hipStream_t stream) {
    const float* text_emb = (const float*)d_in[0];
    const float* emb      = (const float*)d_in[1];
    const float* Wq = (const float*)d_in[2]; const float* bq = (const float*)d_in[3];
    const float* Wk = (const float*)d_in[4]; const float* bk = (const float*)d_in[5];
    const float* Wv = (const float*)d_in[6]; const float* bv = (const float*)d_in[7];
    const float* lw = (const float*)d_in[8]; const float* lb = (const float*)d_in[9];

    float* out = (float*)d_out;
    float* ctx = out;                          // [46,50,768]
    float* rec = out + NB * NS * ND;           // [46,46,50,768]

    float* ws = (float*)d_ws;                  // needs 21.7 MB
    float* Q  = ws;
    float* K  = Q + NB * NS * ND;
    float* V  = K + NB * NS * ND;
    float* Ag = V + NB * NS * ND;              // gamma * Q_trans, [46,50,50]

    qkv_gemm<<<dim3(36, 12, 3), 256, 0, stream>>>(text_emb, emb, Wq, bq, Wk, bk, Wv, bv, Q, K, V);
    attn<<<dim3(NM), 64, 0, stream>>>(Q, K, V, lw, lb, Ag, ctx);
    recur<<<dim3(552), 128, 0, stream>>>(Ag, ctx, rec);
}